// Round 9
// baseline (1036.224 us; speedup 1.0000x reference)
//
#include <hip/hip_runtime.h>
#include <hip/hip_bf16.h>
#include <hip/hip_fp16.h>
#include <math.h>

// ---------------------------------------------------------------------------
// ChaosSSMCore: selective diag-SSM
//   B=128, T=2048, D=256, M = B*T = 262144
//   delta = softplus(x @ Wd^T); decay = exp(-delta*exp(log_a))
//   update = delta * sigmoid(x @ Ws^T) * (x @ Wi^T)
//   states = scan(decay, update);  y = states * silu(x @ Wg^T)
//   out = y @ Wo^T
// du/gate stored in PANEL layout: [pan=n>>4][m][n&15]  (dense per-block writes)
// ---------------------------------------------------------------------------

typedef __attribute__((ext_vector_type(8))) short s16x8;
typedef __attribute__((ext_vector_type(4))) float f32x4;

#define D_DIM 256
#define T_DIM 2048
#define B_DIM 128
#define M_DIM (B_DIM * T_DIM)    // 262144
#define NCHUNK 16
#define CLEN 128                 // T / NCHUNK
#define PANEL ((size_t)M_DIM * 16)

__device__ __forceinline__ unsigned short f2bf(float f) {
    union { float f; unsigned int u; } v; v.f = f;
    unsigned int r = v.u + 0x7fffu + ((v.u >> 16) & 1u);   // RNE
    return (unsigned short)(r >> 16);
}
__device__ __forceinline__ float bf2f(unsigned short s) {
    union { unsigned int u; float f; } v; v.u = ((unsigned int)s) << 16;
    return v.f;
}
__device__ __forceinline__ void gload_lds16(const void* g, void* l) {
    __builtin_amdgcn_global_load_lds(
        (const __attribute__((address_space(1))) unsigned int*)g,
        (__attribute__((address_space(3))) unsigned int*)l, 16, 0, 0);
}

// --------------------------- prep: build Wcat + Wo + ea --------------------
// Wcat[1024][256] bf16, row = n*4 + w, w: 0=delta 1=select 2=in 3=gate.
// Wo slab at +4*65536 (plain [256][256]). ea = exp(log_a).
__global__ __launch_bounds__(256) void prep_kernel(
    const float* __restrict__ W_in, const float* __restrict__ W_select,
    const float* __restrict__ W_gate, const float* __restrict__ W_out,
    const float* __restrict__ W_delta, const float* __restrict__ log_a,
    unsigned short* __restrict__ Wb, float* __restrict__ ea)
{
    int i = blockIdx.x * 256 + threadIdx.x;
    if (i < 4 * 65536) {
        int row = i >> 8, k = i & 255;
        int n = row >> 2, w = row & 3;
        const float* src = (w == 0) ? W_delta : (w == 1) ? W_select
                         : (w == 2) ? W_in    : W_gate;
        Wb[i] = f2bf(src[n * 256 + k]);
    } else if (i < 5 * 65536) {
        Wb[i] = f2bf(W_out[i - 4 * 65536]);
    } else if (i < 5 * 65536 + 256) {
        int j = i - 5 * 65536;
        ea[j] = expf(log_a[j]);
    }
}

// --------------------------- xcast: x fp32 -> bf16 -------------------------
__global__ __launch_bounds__(256) void xcast_kernel(
    const float* __restrict__ x, unsigned short* __restrict__ xb)
{
    size_t i = ((size_t)blockIdx.x * 256 + threadIdx.x) * 8;
    float4 p0 = *(const float4*)(x + i);
    float4 p1 = *(const float4*)(x + i + 4);
    s16x8 a;
    a[0] = (short)f2bf(p0.x); a[1] = (short)f2bf(p0.y);
    a[2] = (short)f2bf(p0.z); a[3] = (short)f2bf(p0.w);
    a[4] = (short)f2bf(p1.x); a[5] = (short)f2bf(p1.y);
    a[6] = (short)f2bf(p1.z); a[7] = (short)f2bf(p1.w);
    *(s16x8*)(xb + i) = a;
}

// --------------------------- gemm_fused v2: W-resident, x streamed ---------
// Block: one nt slice (64 Wcat rows = 16 n x 4 w, 32 KB LDS, staged ONCE,
// one barrier total), then 8 m-tiles of 128 rows. Per tile per wave
// (64m x 32Wrows): full K=256 unrolled = 32 global xf (16B) + 16 swizzled
// wf ds_reads + 64 MFMA, NO barriers -> compiler counted-vmcnt + free wave
// overlap. acc[4][2] = 32 VGPR. D: col=l16=m; regs j=0..3 = w channel.
__global__ __launch_bounds__(256, 3) void gemm_fused_kernel(
    const unsigned short* __restrict__ xb, const unsigned short* __restrict__ Wcat,
    const float* __restrict__ ea,
    __half2* __restrict__ du_p, unsigned short* __restrict__ gate_p)
{
    __shared__ unsigned short wls[64 * 256];   // 32 KB
    int bid = blockIdx.x;
    int wg  = (bid & 7) * 512 + (bid >> 3);    // XCD chunk swizzle (4096%8==0)
    int nt  = wg & 15;                         // 16 nt siblings consecutive
    int mgrp = wg >> 4;                        // 0..255, 8 m-tiles each
    int tid = threadIdx.x, lane = tid & 63, wid = tid >> 6;
    int l16 = lane & 15, lk = lane >> 4;
    int wr = wid >> 1, wc = wid & 1;
    int nb = nt * 64;                          // Wcat row base

    // ---- stage W slice once: LDS[r][gsl] = Wcat[nb+r][gsl ^ (r&7)] ----
#pragma unroll
    for (int i = 0; i < 8; ++i) {
        int e = i * 256 + tid;
        int r = e >> 5, gsl = e & 31;
        int g = gsl ^ (r & 7);
        gload_lds16(Wcat + (size_t)(nb + r) * D_DIM + g * 8,
                    (char*)wls + r * 512 + gsl * 16);
    }
    __syncthreads();   // the only barrier; LDS read-only hereafter

    // per-lane epilogue constants
    float ea0 = ea[nt * 16 + wc * 8 + lk];        // nf = 0
    float ea1 = ea[nt * 16 + wc * 8 + 4 + lk];    // nf = 1

    // W fragment LDS byte addresses (per k-substep, per nf) hoisted
    // row = wc*32 + nf*16 + l16 ; byte = row*512 + ((k*4+lk)^(row&7))*16

    for (int it = 0; it < 8; ++it) {
        int mbase = (mgrp * 8 + it) * 128;
        const unsigned short* xrow =
            xb + (size_t)(mbase + wr * 64 + l16) * D_DIM + lk * 8;

        f32x4 acc[4][2] = {};   // [mf][nf]

#pragma unroll
        for (int k = 0; k < 8; ++k) {
            s16x8 xf[4];
#pragma unroll
            for (int mf = 0; mf < 4; ++mf)
                xf[mf] = *(const s16x8*)(xrow + mf * 16 * D_DIM + k * 32);
            s16x8 wf[2];
#pragma unroll
            for (int nf = 0; nf < 2; ++nf) {
                int row = wc * 32 + nf * 16 + l16;
                int g = (k * 4 + lk) ^ (row & 7);
                wf[nf] = *(const s16x8*)((const char*)wls + row * 512 + g * 16);
            }
#pragma unroll
            for (int nf = 0; nf < 2; ++nf)
#pragma unroll
                for (int mf = 0; mf < 4; ++mf)
                    acc[mf][nf] = __builtin_amdgcn_mfma_f32_16x16x32_bf16(
                        wf[nf], xf[mf], acc[mf][nf], 0, 0, 0);
        }

        // ---- epilogue: acc[mf][nf][j] = {delta,select,in,gate}(m, n_l) ----
#pragma unroll
        for (int nf = 0; nf < 2; ++nf) {
            int n_l = wc * 8 + nf * 4 + lk;       // 0..15 in panel
            float ean = nf ? ea1 : ea0;
#pragma unroll
            for (int mf = 0; mf < 4; ++mf) {
                int m = mbase + wr * 64 + mf * 16 + l16;
                float zd = acc[mf][nf][0];
                float zs = acc[mf][nf][1];
                float zi = acc[mf][nf][2];
                float zg = acc[mf][nf][3];
                float e = __expf(zd);
                float delta = (zd > 15.f) ? zd : __logf(1.f + e);
                float dec = __expf(-delta * ean);
                float sel = 1.f / (1.f + __expf(-zs));
                float upd = delta * sel * zi;
                float g   = zg / (1.f + __expf(-zg));   // silu
                size_t off = (size_t)nt * PANEL + (size_t)m * 16 + n_l;
                du_p[off]   = __floats2half2_rn(dec, upd);
                gate_p[off] = f2bf(g);
            }
        }
    }
}

// --------------------------- scan pass 1: chunk summaries ------------------
__global__ __launch_bounds__(256) void scan1_kernel(
    const __half2* __restrict__ du_p,
    float* __restrict__ cA, float* __restrict__ cS)
{
    int b = blockIdx.x >> 4;       // 128 batches
    int c = blockIdx.x & 15;       // 16 chunks
    int d = threadIdx.x;
    int pan = d >> 4, off = d & 15;
    size_t base = (size_t)pan * PANEL
                + ((size_t)b * T_DIM + (size_t)c * CLEN) * 16 + off;
    float A = 1.f, S = 0.f;
#pragma unroll 4
    for (int t = 0; t < CLEN; ++t) {
        __half2 v = du_p[base + (size_t)t * 16];
        float dc = __low2float(v);
        float up = __high2float(v);
        A *= dc;
        S = fmaf(dc, S, up);
    }
    int idx = (b * NCHUNK + c) * D_DIM + d;
    cA[idx] = A;
    cS[idx] = S;
}

// --------------------------- scan pass 2: chunk carries --------------------
__global__ __launch_bounds__(256) void scan2_kernel(
    const float* __restrict__ cA, const float* __restrict__ cS,
    float* __restrict__ carry)
{
    int b = blockIdx.x;
    int d = threadIdx.x;
    float s = 0.f;
    for (int c = 0; c < NCHUNK; ++c) {
        int idx = (b * NCHUNK + c) * D_DIM + d;
        carry[idx] = s;                 // state entering chunk c
        s = fmaf(cA[idx], s, cS[idx]);
    }
}

// --------------------------- fused scan3 + out-projection ------------------
// block = (b, chunk): scans 128 t-rows (full D), builds y tile in LDS (bf16,
// chunk-XOR-swizzled), then computes out[128 x 256] = y @ Wo^T with MFMA.
__global__ __launch_bounds__(256) void scan_out_kernel(
    const __half2* __restrict__ du_p, const unsigned short* __restrict__ gate_p,
    const float* __restrict__ carry, const unsigned short* __restrict__ Wo,
    float* __restrict__ out)
{
    __shared__ unsigned short yls[128 * 256];   // 64 KB
    int b = blockIdx.x >> 4;
    int c = blockIdx.x & 15;
    int tid = threadIdx.x;

    // ---- phase 1: sequential scan, y -> LDS (swizzled 16B chunks) ----
    {
        int d = tid;
        int pan = d >> 4, poff = d & 15;
        size_t base = (size_t)pan * PANEL
                    + ((size_t)b * T_DIM + (size_t)c * CLEN) * 16 + poff;
        float s = carry[(b * NCHUNK + c) * D_DIM + d];
        int dlo = d & 7, dch = d >> 3;
#pragma unroll 4
        for (int t = 0; t < CLEN; ++t) {
            size_t goff = base + (size_t)t * 16;
            __half2 v = du_p[goff];
            float dc = __low2float(v);
            float up = __high2float(v);
            s = fmaf(dc, s, up);
            float g = bf2f(gate_p[goff]);
            int off = t * 256 + ((dch ^ (t & 7)) << 3) + dlo;
            yls[off] = f2bf(s * g);
        }
    }
    __syncthreads();

    // ---- phase 2: out-tile GEMM, A-frag = Wo rows (global), B-frag = y (LDS)
    int lane = tid & 63, wid = tid >> 6;
    int l16 = lane & 15;
    int lkc = lane >> 4;            // k-subgroup 0..3
    int m0 = (wid >> 1) * 64;
    size_t rbase = (size_t)b * T_DIM + (size_t)c * CLEN;
    int r0 = lkc * 4;

    for (int nblk = 0; nblk < 2; ++nblk) {
        int n0 = (wid & 1) * 64 + nblk * 128;
        f32x4 acc[4][4] = {};
        for (int ks = 0; ks < 8; ++ks) {
            int kb = ks * 32 + lkc * 8;
            s16x8 yf[4];
#pragma unroll
            for (int mf = 0; mf < 4; ++mf) {
                int row = m0 + mf * 16 + l16;
                int chunk = (ks * 4 + lkc) ^ (row & 7);
                yf[mf] = *(const s16x8*)&yls[row * 256 + chunk * 8];
            }
#pragma unroll
            for (int nf = 0; nf < 4; ++nf) {
                s16x8 wfr = *(const s16x8*)(Wo + (size_t)(n0 + nf * 16 + l16) * D_DIM + kb);
#pragma unroll
                for (int mf = 0; mf < 4; ++mf)
                    acc[mf][nf] = __builtin_amdgcn_mfma_f32_16x16x32_bf16(
                        wfr, yf[mf], acc[mf][nf], 0, 0, 0);
            }
        }
        // D col = lane&15 = y row; D rows = n (4 consecutive) -> float4 stores
#pragma unroll
        for (int mf = 0; mf < 4; ++mf) {
            size_t rowg = rbase + m0 + mf * 16 + l16;
#pragma unroll
            for (int nf = 0; nf < 4; ++nf) {
                int n = n0 + nf * 16 + r0;
                *(f32x4*)(out + rowg * D_DIM + n) = acc[mf][nf];
            }
        }
    }
}

// ---------------------------------------------------------------------------
extern "C" void kernel_launch(void* const* d_in, const int* in_sizes, int n_in,
                              void* d_out, int out_size, void* d_ws, size_t ws_size,
                              hipStream_t stream)
{
    const float* x        = (const float*)d_in[0];
    const float* W_in     = (const float*)d_in[1];
    const float* W_select = (const float*)d_in[2];
    const float* W_gate   = (const float*)d_in[3];
    const float* W_out    = (const float*)d_in[4];
    const float* W_delta  = (const float*)d_in[5];
    const float* log_a    = (const float*)d_in[6];
    float* out = (float*)d_out;

    char* ws = (char*)d_ws;
    const size_t MB = 1ull << 20;
    unsigned short* Wb    = (unsigned short*)(ws);               // 640 KB
    float*          ea    = (float*)(ws + 655360);               // 1 KB
    unsigned short* xb    = (unsigned short*)(ws + 1 * MB);      // 128 MB
    __half2*        du    = (__half2*)(ws + 129 * MB);           // 256 MB
    unsigned short* gate  = (unsigned short*)(ws + 385 * MB);    // 128 MB
    float*          cA    = (float*)(ws + 513 * MB);             // 2 MB
    float*          cS    = (float*)(ws + 515 * MB);             // 2 MB
    float*          carry = (float*)(ws + 517 * MB);             // 2 MB
    // total: 519 MB

    prep_kernel<<<1281, 256, 0, stream>>>(W_in, W_select, W_gate, W_out,
                                          W_delta, log_a, Wb, ea);
    xcast_kernel<<<32768, 256, 0, stream>>>(x, xb);
    gemm_fused_kernel<<<4096, 256, 0, stream>>>(xb, Wb, ea, du, gate);
    scan1_kernel<<<B_DIM * NCHUNK, 256, 0, stream>>>(du, cA, cS);
    scan2_kernel<<<B_DIM, 256, 0, stream>>>(cA, cS, carry);
    scan_out_kernel<<<B_DIM * NCHUNK, 256, 0, stream>>>(du, gate, carry,
                                                        Wb + 4 * 65536, out);
}

// Round 10
// 673.681 us; speedup vs baseline: 1.5382x; 1.5382x over previous
//
#include <hip/hip_runtime.h>
#include <hip/hip_bf16.h>
#include <hip/hip_fp16.h>
#include <math.h>

// ---------------------------------------------------------------------------
// ChaosSSMCore: selective diag-SSM
//   B=128, T=2048, D=256, M = B*T = 262144
//   delta = softplus(x @ Wd^T); decay = exp(-delta*exp(log_a))
//   update = delta * sigmoid(x @ Ws^T) * (x @ Wi^T)
//   states = scan(decay, update);  y = states * silu(x @ Wg^T)
//   out = y @ Wo^T
// ---------------------------------------------------------------------------

typedef __attribute__((ext_vector_type(8))) short s16x8;
typedef __attribute__((ext_vector_type(4))) float f32x4;

#define D_DIM 256
#define T_DIM 2048
#define B_DIM 128
#define NCHUNK 16
#define CLEN 128                 // T / NCHUNK
#define BK 64                    // GEMM K-step

__device__ __forceinline__ unsigned short f2bf(float f) {
    union { float f; unsigned int u; } v; v.f = f;
    unsigned int r = v.u + 0x7fffu + ((v.u >> 16) & 1u);   // RNE
    return (unsigned short)(r >> 16);
}
__device__ __forceinline__ float bf2f(unsigned short s) {
    union { unsigned int u; float f; } v; v.u = ((unsigned int)s) << 16;
    return v.f;
}
__device__ __forceinline__ void gload_lds16(const void* g, void* l) {
    __builtin_amdgcn_global_load_lds(
        (const __attribute__((address_space(1))) unsigned int*)g,
        (__attribute__((address_space(3))) unsigned int*)l, 16, 0, 0);
}

// --------------------------- prep: build Wcat + Wo + ea --------------------
// Wcat[1024][256] bf16, row = n*4 + w, w: 0=delta 1=select 2=in 3=gate.
// Wo slab at +4*65536 (plain [256][256]). ea = exp(log_a).
__global__ __launch_bounds__(256) void prep_kernel(
    const float* __restrict__ W_in, const float* __restrict__ W_select,
    const float* __restrict__ W_gate, const float* __restrict__ W_out,
    const float* __restrict__ W_delta, const float* __restrict__ log_a,
    unsigned short* __restrict__ Wb, float* __restrict__ ea)
{
    int i = blockIdx.x * 256 + threadIdx.x;
    if (i < 4 * 65536) {
        int row = i >> 8, k = i & 255;
        int n = row >> 2, w = row & 3;
        const float* src = (w == 0) ? W_delta : (w == 1) ? W_select
                         : (w == 2) ? W_in    : W_gate;
        Wb[i] = f2bf(src[n * 256 + k]);
    } else if (i < 5 * 65536) {
        Wb[i] = f2bf(W_out[i - 4 * 65536]);
    } else if (i < 5 * 65536 + 256) {
        int j = i - 5 * 65536;
        ea[j] = expf(log_a[j]);
    }
}

// --------------------------- xcast: x fp32 -> bf16 -------------------------
__global__ __launch_bounds__(256) void xcast_kernel(
    const float* __restrict__ x, unsigned short* __restrict__ xb)
{
    size_t i = ((size_t)blockIdx.x * 256 + threadIdx.x) * 8;
    float4 p0 = *(const float4*)(x + i);
    float4 p1 = *(const float4*)(x + i + 4);
    s16x8 a;
    a[0] = (short)f2bf(p0.x); a[1] = (short)f2bf(p0.y);
    a[2] = (short)f2bf(p0.z); a[3] = (short)f2bf(p0.w);
    a[4] = (short)f2bf(p1.x); a[5] = (short)f2bf(p1.y);
    a[6] = (short)f2bf(p1.z); a[7] = (short)f2bf(p1.w);
    *(s16x8*)(xb + i) = a;
}

// --------------------------- gemm_fused v3: dbuf pipeline + fused scan1 ----
// Block = 128m x 128 Wcat-rows (= 32 n x 4 W), 4 waves, wave = 64x64 quadrant.
// Double-buffered LDS (2 x 32 KB): STAGE(ks+1) issued BEFORE compute(ks),
// ONE barrier per K-step -> prefetch latency hides under MFMA.
// Block's 128 m-rows = exactly one (b, chunk) (mt = b*16+chunk), so the
// chunk summary (cA = prod decay, cS = local scan) is computed in-kernel via
// a 16 KB scanbuf aliased into buf0 (idle during final K-step): scan1 kernel
// is eliminated. D layout: col(lane&15)=m, regs j=0..3 = w-channel.
__global__ __launch_bounds__(256, 2) void gemm_fused_kernel(
    const unsigned short* __restrict__ xb, const unsigned short* __restrict__ Wcat,
    const float* __restrict__ ea,
    __half2* __restrict__ du, unsigned short* __restrict__ gate,
    float* __restrict__ cA, float* __restrict__ cS)
{
    __shared__ char ldsb[65536];   // buf0 [0,32K), buf1 [32K,64K)
    int bid = blockIdx.x;
    int wg  = (bid & 7) * 2048 + (bid >> 3);   // XCD chunk swizzle (16384%8==0)
    int mt  = wg >> 3;                          // = b*16 + chunk
    int nt  = wg & 7;                           // nt-siblings consecutive
    int mbase = mt * 128;
    int nb = nt * 128;                          // Wcat row base
    int tid = threadIdx.x, lane = tid & 63, wid = tid >> 6;
    int l16 = lane & 15, lk = lane >> 4;
    int wr = wid >> 1, wc = wid & 1;
    int srow = tid >> 3;            // staging: 32 rows per issue-group
    int sgi  = tid & 7;             // staging granule (16B) within row

    f32x4 acc[4][4] = {};           // [mf][nf]

    // ---- prologue: stage K-step 0 into buf0 ----
    {
        int kb = 0;
#pragma unroll
        for (int j = 0; j < 4; ++j) {
            int row = j * 32 + srow;
            int sg  = sgi ^ (row & 7);
            gload_lds16(xb + (size_t)(mbase + row) * D_DIM + kb + sg * 8,
                        ldsb + row * 128 + sgi * 16);
            gload_lds16(Wcat + (size_t)(nb + row) * D_DIM + kb + sg * 8,
                        ldsb + 16384 + row * 128 + sgi * 16);
        }
    }
    __syncthreads();

    for (int ks = 0; ks < 4; ++ks) {
        int bufo = (ks & 1) << 15;
        // ---- issue next-step prefetch FIRST (overlaps with compute) ----
        if (ks < 3) {
            int kb = (ks + 1) * BK;
            int nbo = bufo ^ 32768;
#pragma unroll
            for (int j = 0; j < 4; ++j) {
                int row = j * 32 + srow;
                int sg  = sgi ^ (row & 7);
                gload_lds16(xb + (size_t)(mbase + row) * D_DIM + kb + sg * 8,
                            ldsb + nbo + row * 128 + sgi * 16);
                gload_lds16(Wcat + (size_t)(nb + row) * D_DIM + kb + sg * 8,
                            ldsb + nbo + 16384 + row * 128 + sgi * 16);
            }
        }
        // ---- compute current buffer: 2 kk-halves, 8 ds_read + 16 MFMA ----
#pragma unroll
        for (int kk = 0; kk < 2; ++kk) {
            int gp = ((kk * 4 + lk) ^ (l16 & 7)) * 16;   // swizzled granule
            s16x8 xf[4], wf[4];
#pragma unroll
            for (int mf = 0; mf < 4; ++mf)
                xf[mf] = *(const s16x8*)(ldsb + bufo
                           + (wr * 64 + mf * 16 + l16) * 128 + gp);
#pragma unroll
            for (int nf = 0; nf < 4; ++nf)
                wf[nf] = *(const s16x8*)(ldsb + bufo + 16384
                           + (wc * 64 + nf * 16 + l16) * 128 + gp);
#pragma unroll
            for (int nf = 0; nf < 4; ++nf)
#pragma unroll
                for (int mf = 0; mf < 4; ++mf)
                    acc[mf][nf] = __builtin_amdgcn_mfma_f32_16x16x32_bf16(
                        wf[nf], xf[mf], acc[mf][nf], 0, 0, 0);
        }
        if (ks < 3) __syncthreads();   // drain prefetch + all waves past reads
    }

    // ---- epilogue: acc[mf][nf] = {z_delta, z_select, z_in, z_gate}(m,n) ----
    // scanbuf (16 KB, half2[d=32][t^c]) aliases buf0 (idle: last step read buf1)
    __half2* scanb = (__half2*)ldsb;
    float2*  sums  = (float2*)(ldsb + 16384);
#pragma unroll
    for (int nf = 0; nf < 4; ++nf) {
        int n = nt * 32 + wc * 16 + nf * 4 + lk;
        float ean = ea[n];
        int dl = wc * 16 + nf * 4 + lk;
        int cxor = (dl & 7) << 2;
#pragma unroll
        for (int mf = 0; mf < 4; ++mf) {
            int t = wr * 64 + mf * 16 + l16;
            int m = mbase + t;
            float zd = acc[mf][nf][0];
            float zs = acc[mf][nf][1];
            float zi = acc[mf][nf][2];
            float zg = acc[mf][nf][3];
            float e = __expf(zd);
            float delta = (zd > 15.f) ? zd : __logf(1.f + e);
            float dec = __expf(-delta * ean);
            float sel = 1.f / (1.f + __expf(-zs));
            float upd = delta * sel * zi;
            float g   = zg / (1.f + __expf(-zg));   // silu
            __half2 dv = __floats2half2_rn(dec, upd);
            du[(size_t)m * D_DIM + n] = dv;
            gate[(size_t)m * D_DIM + n] = f2bf(g);
            scanb[dl * 128 + (t ^ cxor)] = dv;
        }
    }
    __syncthreads();

    // ---- fused chunk summary: 8 sub-segments x 16 t, then combine ----
    {
        int dloc = tid & 31, sub = tid >> 5;
        int cxor = (dloc & 7) << 2;
        float A = 1.f, S = 0.f;
        int t0 = sub * 16;
#pragma unroll 4
        for (int i = 0; i < 16; ++i) {
            int t = t0 + i;
            __half2 v = scanb[dloc * 128 + (t ^ cxor)];
            float dc = __low2float(v), up = __high2float(v);
            A *= dc;
            S = fmaf(dc, S, up);
        }
        sums[sub * 32 + dloc] = make_float2(A, S);
    }
    __syncthreads();
    if (tid < 32) {
        float A = 1.f, S = 0.f;
#pragma unroll
        for (int sub = 0; sub < 8; ++sub) {
            float2 as = sums[sub * 32 + tid];
            S = fmaf(as.x, S, as.y);
            A *= as.x;
        }
        int idx = mt * D_DIM + nt * 32 + tid;
        cA[idx] = A;
        cS[idx] = S;
    }
}

// --------------------------- scan pass 2: chunk carries --------------------
__global__ __launch_bounds__(256) void scan2_kernel(
    const float* __restrict__ cA, const float* __restrict__ cS,
    float* __restrict__ carry)
{
    int b = blockIdx.x;
    int d = threadIdx.x;
    float s = 0.f;
    for (int c = 0; c < NCHUNK; ++c) {
        int idx = (b * NCHUNK + c) * D_DIM + d;
        carry[idx] = s;                 // state entering chunk c
        s = fmaf(cA[idx], s, cS[idx]);
    }
}

// --------------------------- fused scan3 + out-projection ------------------
// block = (b, chunk): scans 128 t-rows (full D), builds y tile in LDS (bf16,
// chunk-XOR-swizzled), then computes out[128 x 256] = y @ Wo^T with MFMA.
__global__ __launch_bounds__(256) void scan_out_kernel(
    const __half2* __restrict__ du, const unsigned short* __restrict__ gate,
    const float* __restrict__ carry, const unsigned short* __restrict__ Wo,
    float* __restrict__ out)
{
    __shared__ unsigned short yls[128 * 256];   // 64 KB
    int b = blockIdx.x >> 4;
    int c = blockIdx.x & 15;
    int tid = threadIdx.x;

    // ---- phase 1: sequential scan, y -> LDS (swizzled 16B chunks) ----
    {
        int d = tid;
        size_t base = ((size_t)b * T_DIM + (size_t)c * CLEN) * D_DIM + d;
        float s = carry[(b * NCHUNK + c) * D_DIM + d];
        int dlo = d & 7, dch = d >> 3;
#pragma unroll 4
        for (int t = 0; t < CLEN; ++t) {
            __half2 v = du[base + (size_t)t * D_DIM];
            float dc = __low2float(v);
            float up = __high2float(v);
            s = fmaf(dc, s, up);
            float g = bf2f(gate[base + (size_t)t * D_DIM]);
            int off = t * 256 + ((dch ^ (t & 7)) << 3) + dlo;
            yls[off] = f2bf(s * g);
        }
    }
    __syncthreads();

    // ---- phase 2: out-tile GEMM, A-frag = Wo rows (global), B-frag = y (LDS)
    int lane = tid & 63, wid = tid >> 6;
    int l16 = lane & 15;
    int lkc = lane >> 4;            // k-subgroup 0..3
    int m0 = (wid >> 1) * 64;
    size_t rbase = (size_t)b * T_DIM + (size_t)c * CLEN;
    int r0 = lkc * 4;

    for (int nblk = 0; nblk < 2; ++nblk) {
        int n0 = (wid & 1) * 64 + nblk * 128;
        f32x4 acc[4][4] = {};
        for (int ks = 0; ks < 8; ++ks) {
            int kb = ks * 32 + lkc * 8;
            s16x8 yf[4];
#pragma unroll
            for (int mf = 0; mf < 4; ++mf) {
                int row = m0 + mf * 16 + l16;
                int chunk = (ks * 4 + lkc) ^ (row & 7);
                yf[mf] = *(const s16x8*)&yls[row * 256 + chunk * 8];
            }
#pragma unroll
            for (int nf = 0; nf < 4; ++nf) {
                s16x8 wfr = *(const s16x8*)(Wo + (size_t)(n0 + nf * 16 + l16) * D_DIM + kb);
#pragma unroll
                for (int mf = 0; mf < 4; ++mf)
                    acc[mf][nf] = __builtin_amdgcn_mfma_f32_16x16x32_bf16(
                        wfr, yf[mf], acc[mf][nf], 0, 0, 0);
            }
        }
        // D col = lane&15 = y row; D rows = n (4 consecutive) -> float4 stores
#pragma unroll
        for (int mf = 0; mf < 4; ++mf) {
            size_t rowg = rbase + m0 + mf * 16 + l16;
#pragma unroll
            for (int nf = 0; nf < 4; ++nf) {
                int n = n0 + nf * 16 + r0;
                *(f32x4*)(out + rowg * D_DIM + n) = acc[mf][nf];
            }
        }
    }
}

// ---------------------------------------------------------------------------
extern "C" void kernel_launch(void* const* d_in, const int* in_sizes, int n_in,
                              void* d_out, int out_size, void* d_ws, size_t ws_size,
                              hipStream_t stream)
{
    const float* x        = (const float*)d_in[0];
    const float* W_in     = (const float*)d_in[1];
    const float* W_select = (const float*)d_in[2];
    const float* W_gate   = (const float*)d_in[3];
    const float* W_out    = (const float*)d_in[4];
    const float* W_delta  = (const float*)d_in[5];
    const float* log_a    = (const float*)d_in[6];
    float* out = (float*)d_out;

    char* ws = (char*)d_ws;
    const size_t MB = 1ull << 20;
    unsigned short* Wb    = (unsigned short*)(ws);               // 640 KB
    float*          ea    = (float*)(ws + 655360);               // 1 KB
    unsigned short* xb    = (unsigned short*)(ws + 1 * MB);      // 128 MB
    __half2*        du    = (__half2*)(ws + 129 * MB);           // 256 MB
    unsigned short* gate  = (unsigned short*)(ws + 385 * MB);    // 128 MB
    float*          cA    = (float*)(ws + 513 * MB);             // 2 MB
    float*          cS    = (float*)(ws + 515 * MB);             // 2 MB
    float*          carry = (float*)(ws + 517 * MB);             // 2 MB
    // total: 519 MB

    prep_kernel<<<1281, 256, 0, stream>>>(W_in, W_select, W_gate, W_out,
                                          W_delta, log_a, Wb, ea);
    xcast_kernel<<<32768, 256, 0, stream>>>(x, xb);
    gemm_fused_kernel<<<16384, 256, 0, stream>>>(xb, Wb, ea, du, gate, cA, cS);
    scan2_kernel<<<B_DIM, 256, 0, stream>>>(cA, cS, carry);
    scan_out_kernel<<<B_DIM * NCHUNK, 256, 0, stream>>>(du, gate, carry,
                                                        Wb + 4 * 65536, out);
}

// Round 11
// 647.030 us; speedup vs baseline: 1.6015x; 1.0412x over previous
//
#include <hip/hip_runtime.h>
#include <hip/hip_bf16.h>
#include <hip/hip_fp16.h>
#include <math.h>

// ---------------------------------------------------------------------------
// ChaosSSMCore: selective diag-SSM
//   B=128, T=2048, D=256, M = B*T = 262144
//   delta = softplus(x @ Wd^T); decay = exp(-delta*exp(log_a))
//   update = delta * sigmoid(x @ Ws^T) * (x @ Wi^T)
//   states = scan(decay, update);  y = states * silu(x @ Wg^T)
//   out = y @ Wo^T
// ---------------------------------------------------------------------------

typedef __attribute__((ext_vector_type(8))) short s16x8;
typedef __attribute__((ext_vector_type(4))) float f32x4;

#define D_DIM 256
#define T_DIM 2048
#define B_DIM 128
#define NCHUNK 16
#define CLEN 128                 // T / NCHUNK
#define BK 64                    // GEMM K-step

__device__ __forceinline__ unsigned short f2bf(float f) {
    union { float f; unsigned int u; } v; v.f = f;
    unsigned int r = v.u + 0x7fffu + ((v.u >> 16) & 1u);   // RNE
    return (unsigned short)(r >> 16);
}
__device__ __forceinline__ float bf2f(unsigned short s) {
    union { unsigned int u; float f; } v; v.u = ((unsigned int)s) << 16;
    return v.f;
}
__device__ __forceinline__ s16x8 cvt2(float4 p0, float4 p1) {
    union { __hip_bfloat162 h; unsigned int u; } c0, c1, c2, c3;
    c0.h = __float22bfloat162_rn({p0.x, p0.y});
    c1.h = __float22bfloat162_rn({p0.z, p0.w});
    c2.h = __float22bfloat162_rn({p1.x, p1.y});
    c3.h = __float22bfloat162_rn({p1.z, p1.w});
    union { unsigned int u[4]; s16x8 v; } r;
    r.u[0] = c0.u; r.u[1] = c1.u; r.u[2] = c2.u; r.u[3] = c3.u;
    return r.v;
}
__device__ __forceinline__ void gload_lds16(const void* g, void* l) {
    __builtin_amdgcn_global_load_lds(
        (const __attribute__((address_space(1))) unsigned int*)g,
        (__attribute__((address_space(3))) unsigned int*)l, 16, 0, 0);
}

// --------------------------- prep: build Wcat + Wo + ea --------------------
// Wcat[1024][256] bf16, row = n*4 + w, w: 0=delta 1=select 2=in 3=gate.
// Wo slab at +4*65536 (plain [256][256]). ea = exp(log_a).
__global__ __launch_bounds__(256) void prep_kernel(
    const float* __restrict__ W_in, const float* __restrict__ W_select,
    const float* __restrict__ W_gate, const float* __restrict__ W_out,
    const float* __restrict__ W_delta, const float* __restrict__ log_a,
    unsigned short* __restrict__ Wb, float* __restrict__ ea)
{
    int i = blockIdx.x * 256 + threadIdx.x;
    if (i < 4 * 65536) {
        int row = i >> 8, k = i & 255;
        int n = row >> 2, w = row & 3;
        const float* src = (w == 0) ? W_delta : (w == 1) ? W_select
                         : (w == 2) ? W_in    : W_gate;
        Wb[i] = f2bf(src[n * 256 + k]);
    } else if (i < 5 * 65536) {
        Wb[i] = f2bf(W_out[i - 4 * 65536]);
    } else if (i < 5 * 65536 + 256) {
        int j = i - 5 * 65536;
        ea[j] = expf(log_a[j]);
    }
}

// --------------------------- gemm_fused v4 ---------------------------------
// Round-8 structure (single 2-phase buffer, 3 blocks/CU) +:
//  - A staged as RAW FP32 x via global_load_lds (no xcast kernel, no xb):
//    A-LDS 128 rows x 256B, granule(16B)-XOR g^=(row&7); fragment = two
//    ds_read_b128 (g0^s, (g0+1)^s) + in-reg cvt to bf16.
//  - B (Wcat bf16) path byte-identical to round 8 (0 conflicts measured).
//  - fused scan1 epilogue: scanbuf STRIDE-129 half2 (129 = 1 mod 32 banks),
//    aliased into the A region after a sync; emits cA/cS (scan1 kernel gone).
// Block = 128m x 128 Wcat-rows (32 n x 4 w); mt = b*16+chunk. 4 waves 64x64.
__global__ __launch_bounds__(256, 3) void gemm_fused_kernel(
    const float* __restrict__ x, const unsigned short* __restrict__ Wcat,
    const float* __restrict__ ea,
    __half2* __restrict__ du, unsigned short* __restrict__ gate,
    float* __restrict__ cA, float* __restrict__ cS)
{
    __shared__ char ldsb[49152];   // A fp32 [0,32K), B bf16 [32K,48K)
    int bid = blockIdx.x;
    int wg  = (bid & 7) * 2048 + (bid >> 3);   // XCD chunk swizzle (16384%8==0)
    int mt  = wg >> 3;                          // = b*16 + chunk
    int nt  = wg & 7;
    int mbase = mt * 128;
    int nb = nt * 128;                          // Wcat row base
    int tid = threadIdx.x, lane = tid & 63, wid = tid >> 6;
    int l16 = lane & 15, lk = lane >> 4;
    int wr = wid >> 1, wc = wid & 1;

    f32x4 acc[4][4] = {};           // [mf][nf]

    for (int ks = 0; ks < 4; ++ks) {
        int kb = ks * BK;
        // ---- stage A (x fp32): 2048 granules, 8 per thread ----
#pragma unroll
        for (int j = 0; j < 8; ++j) {
            int e = j * 256 + tid;
            int row = e >> 4, gsl = e & 15;
            int g = gsl ^ (row & 7);
            gload_lds16(x + (size_t)(mbase + row) * D_DIM + kb + g * 4,
                        ldsb + e * 16);
        }
        // ---- stage B (Wcat bf16): 1024 granules, 4 per thread ----
#pragma unroll
        for (int j = 0; j < 4; ++j) {
            int e = j * 256 + tid;
            int row = e >> 3, gsl = e & 7;
            int g = gsl ^ (row & 7);
            gload_lds16(Wcat + (size_t)(nb + row) * D_DIM + kb + g * 8,
                        ldsb + 32768 + e * 16);
        }
        __syncthreads();   // drains vmcnt -> staged data visible

        // ---- compute: 2 kk-halves; per half 8 A-reads + 4 B-reads + 16 MFMA
#pragma unroll
        for (int kk = 0; kk < 2; ++kk) {
            s16x8 xf[4], wf[4];
#pragma unroll
            for (int mf = 0; mf < 4; ++mf) {
                int rowA = wr * 64 + mf * 16 + l16;
                int s = rowA & 7;
                int g0 = kk * 8 + lk * 2;   // even
                float4 a0 = *(const float4*)(ldsb + rowA * 256 + ((g0 ^ s) * 16));
                float4 a1 = *(const float4*)(ldsb + rowA * 256 + (((g0 + 1) ^ s) * 16));
                xf[mf] = cvt2(a0, a1);
            }
            int gp = ((kk * 4 + lk) ^ (l16 & 7)) * 16;
#pragma unroll
            for (int nf = 0; nf < 4; ++nf)
                wf[nf] = *(const s16x8*)(ldsb + 32768
                           + (wc * 64 + nf * 16 + l16) * 128 + gp);
#pragma unroll
            for (int nf = 0; nf < 4; ++nf)
#pragma unroll
                for (int mf = 0; mf < 4; ++mf)
                    acc[mf][nf] = __builtin_amdgcn_mfma_f32_16x16x32_bf16(
                        wf[nf], xf[mf], acc[mf][nf], 0, 0, 0);
        }
        __syncthreads();   // all reads done before next stage / scanbuf alias
    }

    // ---- epilogue: acc[mf][nf] = {z_delta, z_select, z_in, z_gate}(m,n) ----
    // scanbuf aliases A region: half2[dl][t] stride 129 (bank-clean), 16.5 KB
    __half2* scanb = (__half2*)ldsb;
    float2*  sums  = (float2*)(ldsb + 20480);
#pragma unroll
    for (int nf = 0; nf < 4; ++nf) {
        int n = nt * 32 + wc * 16 + nf * 4 + lk;
        float ean = ea[n];
        int dl = wc * 16 + nf * 4 + lk;
#pragma unroll
        for (int mf = 0; mf < 4; ++mf) {
            int t = wr * 64 + mf * 16 + l16;
            int m = mbase + t;
            float zd = acc[mf][nf][0];
            float zs = acc[mf][nf][1];
            float zi = acc[mf][nf][2];
            float zg = acc[mf][nf][3];
            float e = __expf(zd);
            float delta = (zd > 15.f) ? zd : __logf(1.f + e);
            float dec = __expf(-delta * ean);
            float sel = 1.f / (1.f + __expf(-zs));
            float upd = delta * sel * zi;
            float g   = zg / (1.f + __expf(-zg));   // silu
            __half2 dv = __floats2half2_rn(dec, upd);
            du[(size_t)m * D_DIM + n] = dv;
            gate[(size_t)m * D_DIM + n] = f2bf(g);
            scanb[dl * 129 + t] = dv;
        }
    }
    __syncthreads();

    // ---- fused chunk summary: 8 sub-segments x 16 t, then combine ----
    {
        int dloc = tid & 31, sub = tid >> 5;
        float A = 1.f, S = 0.f;
        int t0 = sub * 16;
#pragma unroll 4
        for (int i = 0; i < 16; ++i) {
            __half2 v = scanb[dloc * 129 + t0 + i];
            float dc = __low2float(v), up = __high2float(v);
            A *= dc;
            S = fmaf(dc, S, up);
        }
        sums[sub * 32 + dloc] = make_float2(A, S);
    }
    __syncthreads();
    if (tid < 32) {
        float A = 1.f, S = 0.f;
#pragma unroll
        for (int sub = 0; sub < 8; ++sub) {
            float2 as = sums[sub * 32 + tid];
            S = fmaf(as.x, S, as.y);
            A *= as.x;
        }
        int idx = mt * D_DIM + nt * 32 + tid;
        cA[idx] = A;
        cS[idx] = S;
    }
}

// --------------------------- scan pass 2: chunk carries --------------------
__global__ __launch_bounds__(256) void scan2_kernel(
    const float* __restrict__ cA, const float* __restrict__ cS,
    float* __restrict__ carry)
{
    int b = blockIdx.x;
    int d = threadIdx.x;
    float s = 0.f;
    for (int c = 0; c < NCHUNK; ++c) {
        int idx = (b * NCHUNK + c) * D_DIM + d;
        carry[idx] = s;                 // state entering chunk c
        s = fmaf(cA[idx], s, cS[idx]);
    }
}

// --------------------------- fused scan3 + out-projection ------------------
// block = (b, chunk): scans 128 t-rows (full D), builds y tile in LDS (bf16,
// chunk-XOR-swizzled), then computes out[128 x 256] = y @ Wo^T with MFMA.
__global__ __launch_bounds__(256) void scan_out_kernel(
    const __half2* __restrict__ du, const unsigned short* __restrict__ gate,
    const float* __restrict__ carry, const unsigned short* __restrict__ Wo,
    float* __restrict__ out)
{
    __shared__ unsigned short yls[128 * 256];   // 64 KB
    int b = blockIdx.x >> 4;
    int c = blockIdx.x & 15;
    int tid = threadIdx.x;

    // ---- phase 1: sequential scan, y -> LDS (swizzled 16B chunks) ----
    {
        int d = tid;
        size_t base = ((size_t)b * T_DIM + (size_t)c * CLEN) * D_DIM + d;
        float s = carry[(b * NCHUNK + c) * D_DIM + d];
        int dlo = d & 7, dch = d >> 3;
#pragma unroll 4
        for (int t = 0; t < CLEN; ++t) {
            __half2 v = du[base + (size_t)t * D_DIM];
            float dc = __low2float(v);
            float up = __high2float(v);
            s = fmaf(dc, s, up);
            float g = bf2f(gate[base + (size_t)t * D_DIM]);
            int off = t * 256 + ((dch ^ (t & 7)) << 3) + dlo;
            yls[off] = f2bf(s * g);
        }
    }
    __syncthreads();

    // ---- phase 2: out-tile GEMM, A-frag = Wo rows (global), B-frag = y (LDS)
    int lane = tid & 63, wid = tid >> 6;
    int l16 = lane & 15;
    int lkc = lane >> 4;            // k-subgroup 0..3
    int m0 = (wid >> 1) * 64;
    size_t rbase = (size_t)b * T_DIM + (size_t)c * CLEN;
    int r0 = lkc * 4;

    for (int nblk = 0; nblk < 2; ++nblk) {
        int n0 = (wid & 1) * 64 + nblk * 128;
        f32x4 acc[4][4] = {};
        for (int ks = 0; ks < 8; ++ks) {
            int kb = ks * 32 + lkc * 8;
            s16x8 yf[4];
#pragma unroll
            for (int mf = 0; mf < 4; ++mf) {
                int row = m0 + mf * 16 + l16;
                int chunk = (ks * 4 + lkc) ^ (row & 7);
                yf[mf] = *(const s16x8*)&yls[row * 256 + chunk * 8];
            }
#pragma unroll
            for (int nf = 0; nf < 4; ++nf) {
                s16x8 wfr = *(const s16x8*)(Wo + (size_t)(n0 + nf * 16 + l16) * D_DIM + kb);
#pragma unroll
                for (int mf = 0; mf < 4; ++mf)
                    acc[mf][nf] = __builtin_amdgcn_mfma_f32_16x16x32_bf16(
                        wfr, yf[mf], acc[mf][nf], 0, 0, 0);
            }
        }
        // D col = lane&15 = y row; D rows = n (4 consecutive) -> float4 stores
#pragma unroll
        for (int mf = 0; mf < 4; ++mf) {
            size_t rowg = rbase + m0 + mf * 16 + l16;
#pragma unroll
            for (int nf = 0; nf < 4; ++nf) {
                int n = n0 + nf * 16 + r0;
                *(f32x4*)(out + rowg * D_DIM + n) = acc[mf][nf];
            }
        }
    }
}

// ---------------------------------------------------------------------------
extern "C" void kernel_launch(void* const* d_in, const int* in_sizes, int n_in,
                              void* d_out, int out_size, void* d_ws, size_t ws_size,
                              hipStream_t stream)
{
    const float* x        = (const float*)d_in[0];
    const float* W_in     = (const float*)d_in[1];
    const float* W_select = (const float*)d_in[2];
    const float* W_gate   = (const float*)d_in[3];
    const float* W_out    = (const float*)d_in[4];
    const float* W_delta  = (const float*)d_in[5];
    const float* log_a    = (const float*)d_in[6];
    float* out = (float*)d_out;

    char* ws = (char*)d_ws;
    const size_t MB = 1ull << 20;
    unsigned short* Wb    = (unsigned short*)(ws);               // 640 KB
    float*          ea    = (float*)(ws + 655360);               // 1 KB
    __half2*        du    = (__half2*)(ws + 1 * MB);             // 256 MB
    unsigned short* gate  = (unsigned short*)(ws + 257 * MB);    // 128 MB
    float*          cA    = (float*)(ws + 385 * MB);             // 2 MB
    float*          cS    = (float*)(ws + 387 * MB);             // 2 MB
    float*          carry = (float*)(ws + 389 * MB);             // 2 MB
    // total: 391 MB

    prep_kernel<<<1281, 256, 0, stream>>>(W_in, W_select, W_gate, W_out,
                                          W_delta, log_a, Wb, ea);
    gemm_fused_kernel<<<16384, 256, 0, stream>>>(x, Wb, ea, du, gate, cA, cS);
    scan2_kernel<<<B_DIM, 256, 0, stream>>>(cA, cS, carry);
    scan_out_kernel<<<B_DIM * NCHUNK, 256, 0, stream>>>(du, gate, carry,
                                                        Wb + 4 * 65536, out);
}